// Round 2
// baseline (8669.686 us; speedup 1.0000x reference)
//
#include <hip/hip_runtime.h>

#define BB 256
#define SS 336
#define HH 512
#define NT 431   // output time steps
#define NU 432   // total cell steps (336 enc + 96 pred)

typedef __attribute__((ext_vector_type(8))) short bf16x8;
typedef __attribute__((ext_vector_type(16))) float f32x16;

// ---------------- ws layout (bytes) ----------------
// wFrag : 4 matrices (lin_whh, lin_wih, quat_whh, quat_wih), fragment-order bf16
//         each 2048*512*2B = 2 MB                              @ 0
// hbuf  : 2 parity * 2 branch * 8rb*32kb*64lane*8 bf16 (1 MB)  @ 8388608
// bar   : 8 group counters, 128B apart (4 KB)                  @ 9437184
// M     : [2][2048][4] f32                                     @ 10485760
// bE    : [2][2048] f32                                        @ 10551296
// bP    : [2][2048] f32                                        @ 10567680

__device__ inline unsigned short f2bf(float f) {
    unsigned int u = __float_as_uint(f);
    unsigned int r = (u + 0x7fffu + ((u >> 16) & 1u)) >> 16;
    return (unsigned short)r;
}
__device__ inline float sigm(float x) { return 1.f / (1.f + __expf(-x)); }
__device__ inline float tanh_(float x) { return 2.f / (1.f + __expf(-2.f * x)) - 1.f; }

// Convert the 4 recurrent weight matrices [2048][512] f32 -> bf16 in MFMA
// B-fragment order: [mat][cg(32)][csub(2)][kb(32)][lane(64)][8]
__global__ void k_wfrag(const float* __restrict__ w0, const float* __restrict__ w1,
                        const float* __restrict__ w2, const float* __restrict__ w3,
                        unsigned short* __restrict__ wfrag) {
    int idx = blockIdx.x * 256 + threadIdx.x;      // 0 .. 524287
    int mat = idx >> 17;
    int t = idx & 131071;
    int lane = t & 63;
    int kb = (t >> 6) & 31;
    int csub = (t >> 11) & 1;
    int cg = t >> 12;                               // 0..31
    const float* W = mat == 0 ? w0 : (mat == 1 ? w1 : (mat == 2 ? w2 : w3));
    int n_local = csub * 32 + (lane & 31);          // local gate-col 0..63
    int n = (n_local >> 4) * 512 + cg * 16 + (n_local & 15);  // global gate row
    int k0 = kb * 16 + (lane >> 5) * 8;
    const float* src = W + n * 512 + k0;
    unsigned short us[8];
#pragma unroll
    for (int j = 0; j < 8; ++j) us[j] = f2bf(src[j]);
    int4 v;
    v.x = us[0] | (us[1] << 16); v.y = us[2] | (us[3] << 16);
    v.z = us[4] | (us[5] << 16); v.w = us[6] | (us[7] << 16);
    ((int4*)wfrag)[idx] = v;
}

// M = Wih@We  [2][2048][4], bE = Wih@be + bih + bhh, bP = bih + bhh
__global__ void k_mbias(const float* __restrict__ lin_wih, const float* __restrict__ quat_wih,
                        const float* __restrict__ lin_enc_w, const float* __restrict__ quat_enc_w,
                        const float* __restrict__ lin_enc_b, const float* __restrict__ quat_enc_b,
                        const float* __restrict__ lin_bih, const float* __restrict__ lin_bhh,
                        const float* __restrict__ quat_bih, const float* __restrict__ quat_bhh,
                        float* __restrict__ M, float* __restrict__ bE, float* __restrict__ bP) {
    int gid = blockIdx.x * 256 + threadIdx.x;      // 0..4095
    int branch = gid >> 11;
    int n = gid & 2047;
    int nf = 3 + branch;
    const float* Wih = branch ? quat_wih : lin_wih;
    const float* We  = branch ? quat_enc_w : lin_enc_w;
    const float* be  = branch ? quat_enc_b : lin_enc_b;
    const float* bih = branch ? quat_bih : lin_bih;
    const float* bhh = branch ? quat_bhh : lin_bhh;
    float m[4] = {0.f, 0.f, 0.f, 0.f};
    float bs = 0.f;
    for (int j = 0; j < 512; ++j) {
        float w = Wih[n * 512 + j];
#pragma unroll
        for (int kf = 0; kf < 4; ++kf)
            if (kf < nf) m[kf] += w * We[j * nf + kf];
        bs += w * be[j];
    }
    float* Mp = M + (branch * 2048 + n) * 4;
#pragma unroll
    for (int kf = 0; kf < 4; ++kf) Mp[kf] = m[kf];
    bE[branch * 2048 + n] = bs + bih[n] + bhh[n];
    bP[branch * 2048 + n] = bih[n] + bhh[n];
}

__global__ void k_zero(int4* __restrict__ p) {
    int idx = blockIdx.x * 256 + threadIdx.x;      // 257 blocks: hbuf (1 MB) + counters (4 KB)
    p[idx] = int4{0, 0, 0, 0};
}

__global__ void k_initout(float* __restrict__ out,
                          const float* __restrict__ lb, const float* __restrict__ qb) {
    int idx = blockIdx.x * 256 + threadIdx.x;      // exactly 772352
    if (idx < BB * NT * 7) {
        int d = idx % 7;
        out[idx] = d < 3 ? lb[d] : qb[d - 3];
    }
}

// Persistent kernel: all 432 LSTM steps for both branches.
// 256 blocks x 256 threads, 1 block/CU (guaranteed co-resident: 256 blocks on 256 CUs,
// __launch_bounds__(256,1), ~23 KB LDS). blk: branch = blk>>7, rg = (blk>>5)&3, cg = blk&31.
// Cross-block dependency exists only among the 32 cg-blocks sharing (branch, rg)
// => 8 independent groups of 32 blocks, synced via per-group LLC counters
// (release-RMW arrive / relaxed-spin + agent acquire-fence wait).
__global__ __launch_bounds__(256, 1) void k_persist(
    const float* __restrict__ x,
    const unsigned short* __restrict__ wfrag,
    const float* __restrict__ M, const float* __restrict__ bE, const float* __restrict__ bP,
    const float* __restrict__ lin_dec_w, const float* __restrict__ quat_dec_w,
    unsigned short* __restrict__ hbuf,
    float* __restrict__ out,
    unsigned int* __restrict__ bar) {
    __shared__ float g_lds[64 * 65];
    __shared__ float h_tile[64 * 17];
    __shared__ float mE[256];        // [gate][jj][kf]
    __shared__ float bEs[64];        // [gate][jj]
    __shared__ float bPs[64];
    __shared__ float wds[64];        // [d][j2]

    const int tid = threadIdx.x;
    const int lane = tid & 63;
    const int wv = tid >> 6;
    const int rsub = wv & 1, csub = wv >> 1;
    const int blk = blockIdx.x;
    const int branch = blk >> 7;
    const int rg = (blk >> 5) & 3;
    const int cg = blk & 31;
    const int group = blk >> 5;                 // 0..7
    const int nf = 3 + branch;
    const int row = tid & 63;
    const int jbase = tid >> 6;
    const int b = rg * 64 + row;

    // ---- one-time LDS staging of per-block constants
    {
        int gate = tid >> 6, jj = (tid >> 2) & 15, kf = tid & 3;
        mE[tid] = M[(size_t)(branch * 2048 + gate * 512 + cg * 16 + jj) * 4 + kf];
    }
    if (tid < 64) {
        int gate = tid >> 4, jj = tid & 15;
        bEs[tid] = bE[branch * 2048 + gate * 512 + cg * 16 + jj];
        bPs[tid] = bP[branch * 2048 + gate * 512 + cg * 16 + jj];
        const float* dw = branch ? quat_dec_w : lin_dec_w;
        wds[tid] = (gate < nf) ? dw[gate * 512 + cg * 16 + jj] : 0.f;
    }

    // ---- register-resident weight fragments for this wave (enc matrix first)
    const int4* BpE = (const int4*)wfrag + (size_t)(branch * 2) * 131072
                      + ((cg * 2 + csub) * 32) * 64 + lane;
    const int4* BpP = BpE + 131072;
    int4 bw[32];
#pragma unroll
    for (int kb = 0; kb < 32; ++kb) bw[kb] = BpE[kb * 64];

    float creg[4] = {0.f, 0.f, 0.f, 0.f};
    unsigned int* ctr = bar + group * 32;       // 128 B apart

    __syncthreads();

    for (int u = 0; u < NU; ++u) {
        const int is_enc = (u < SS);

        // x loads: independent of the barrier, issue early
        float xv0 = 0.f, xv1 = 0.f, xv2 = 0.f, xv3 = 0.f;
        if (is_enc) {
            const float* xp = x + ((size_t)b * SS + u) * 7 + branch * 3;
            xv0 = xp[0]; xv1 = xp[1]; xv2 = xp[2];
            if (branch) xv3 = xp[3];
        }
        if (u == SS) {      // enc -> pred weight switch (Whh -> Wih)
#pragma unroll
            for (int kb = 0; kb < 32; ++kb) bw[kb] = BpP[kb * 64];
        }

        // ---- group barrier: wait until all 32 peers finished step u-1
        if (u > 0) {
            if (tid == 0) {
                unsigned int tgt = 32u * (unsigned int)u;
                while (__hip_atomic_load(ctr, __ATOMIC_RELAXED, __HIP_MEMORY_SCOPE_AGENT) < tgt) {
                    __builtin_amdgcn_s_sleep(1);
                }
            }
            __syncthreads();
            __builtin_amdgcn_fence(__ATOMIC_ACQUIRE, "agent");
        }

        // ---- GEMM: g[64 x 64] = h[64 x 512] @ W_sliceT, B from registers
        const int4* Ap = (const int4*)hbuf + (size_t)(u & 1) * 32768 + (size_t)branch * 16384
                         + (rg * 2 + rsub) * 2048 + lane;
        f32x16 acc0 = {};
        f32x16 acc1 = {};
#pragma unroll
        for (int kb = 0; kb < 32; kb += 2) {
            int4 a0 = Ap[kb * 64];
            int4 a1 = Ap[(kb + 1) * 64];
            acc0 = __builtin_amdgcn_mfma_f32_32x32x16_bf16(*(const bf16x8*)&a0, *(const bf16x8*)&bw[kb], acc0, 0, 0, 0);
            acc1 = __builtin_amdgcn_mfma_f32_32x32x16_bf16(*(const bf16x8*)&a1, *(const bf16x8*)&bw[kb + 1], acc1, 0, 0, 0);
        }
        // C layout (32x32): col = lane&31, row = (reg&3) + 8*(reg>>2) + 4*(lane>>5)
        int col_l = csub * 32 + (lane & 31);
        int rbase = rsub * 32 + 4 * (lane >> 5);
#pragma unroll
        for (int r = 0; r < 16; ++r) {
            int row_l = rbase + (r & 3) + 8 * (r >> 2);
            g_lds[row_l * 65 + col_l] = acc0[r] + acc1[r];
        }
        __syncthreads();

        // ---- gates: thread handles row, jj = jbase*4 + p
#pragma unroll
        for (int p = 0; p < 4; ++p) {
            int jj = jbase * 4 + p;
            float gi = g_lds[row * 65 + jj];
            float gf = g_lds[row * 65 + 16 + jj];
            float gc = g_lds[row * 65 + 32 + jj];
            float go = g_lds[row * 65 + 48 + jj];
            if (is_enc) {
                int j4 = jj * 4;
                gi += bEs[jj]      + xv0 * mE[j4]       + xv1 * mE[j4 + 1]       + xv2 * mE[j4 + 2]       + xv3 * mE[j4 + 3];
                gf += bEs[16 + jj] + xv0 * mE[64 + j4]  + xv1 * mE[64 + j4 + 1]  + xv2 * mE[64 + j4 + 2]  + xv3 * mE[64 + j4 + 3];
                gc += bEs[32 + jj] + xv0 * mE[128 + j4] + xv1 * mE[128 + j4 + 1] + xv2 * mE[128 + j4 + 2] + xv3 * mE[128 + j4 + 3];
                go += bEs[48 + jj] + xv0 * mE[192 + j4] + xv1 * mE[192 + j4 + 1] + xv2 * mE[192 + j4 + 2] + xv3 * mE[192 + j4 + 3];
            } else {
                gi += bPs[jj];
                gf += bPs[16 + jj];
                gc += bPs[32 + jj];
                go += bPs[48 + jj];
            }
            float iv = sigm(gi), fv = sigm(gf), gv = tanh_(gc), ov = sigm(go);
            float cn;
            if (is_enc) {
                cn = fv * creg[p] + iv * gv;
                creg[p] = cn;
            } else {
                cn = iv * gv;   // pred steps start from zero state
            }
            h_tile[row * 17 + jj] = ov * tanh_(cn);
        }
        __syncthreads();

        // ---- write h_new (bf16, fragment order) for the next step's A operand
        if (tid < 128) {
            int chunk = tid >> 6;
            int l = tid & 63;
            int row_l = chunk * 32 + (l & 31);
            int jh = (l >> 5) * 8;
            unsigned short us[8];
#pragma unroll
            for (int j = 0; j < 8; ++j) us[j] = f2bf(h_tile[row_l * 17 + jh + j]);
            int4 v;
            v.x = us[0] | (us[1] << 16); v.y = us[2] | (us[3] << 16);
            v.z = us[4] | (us[5] << 16); v.w = us[6] | (us[7] << 16);
            int rb = rg * 2 + chunk;
            ((int4*)hbuf)[(size_t)((u + 1) & 1) * 32768 + (size_t)branch * 16384
                          + (rb * 32 + cg) * 64 + l] = v;
        }
        __syncthreads();    // drains all h stores to L2 (vmcnt(0) before s_barrier)

        // ---- arrive: release our h writes to the group (release RMW -> L2 writeback)
        if (tid == 0) {
            __hip_atomic_fetch_add(ctr, 1u, __ATOMIC_RELEASE, __HIP_MEMORY_SCOPE_AGENT);
        }

        // ---- fused decoder (off the critical path, after arrive)
        if (u >= 1) {
            if (jbase < nf) {
                float s = 0.f;
#pragma unroll
                for (int j2 = 0; j2 < 16; ++j2) s += h_tile[row * 17 + j2] * wds[jbase * 16 + j2];
                unsafeAtomicAdd(out + ((size_t)b * NT + (u - 1)) * 7 + branch * 3 + jbase, s);
            }
        }
    }
}

extern "C" void kernel_launch(void* const* d_in, const int* in_sizes, int n_in,
                              void* d_out, int out_size, void* d_ws, size_t ws_size,
                              hipStream_t stream) {
    const float* x          = (const float*)d_in[0];
    const float* lin_enc_w  = (const float*)d_in[1];
    const float* lin_enc_b  = (const float*)d_in[2];
    const float* quat_enc_w = (const float*)d_in[3];
    const float* quat_enc_b = (const float*)d_in[4];
    const float* lin_wih    = (const float*)d_in[5];
    const float* lin_whh    = (const float*)d_in[6];
    const float* lin_bih    = (const float*)d_in[7];
    const float* lin_bhh    = (const float*)d_in[8];
    const float* quat_wih   = (const float*)d_in[9];
    const float* quat_whh   = (const float*)d_in[10];
    const float* quat_bih   = (const float*)d_in[11];
    const float* quat_bhh   = (const float*)d_in[12];
    const float* lin_dec_w  = (const float*)d_in[13];
    const float* lin_dec_b  = (const float*)d_in[14];
    const float* quat_dec_w = (const float*)d_in[15];
    const float* quat_dec_b = (const float*)d_in[16];
    float* out = (float*)d_out;
    char* ws = (char*)d_ws;

    unsigned short* wfrag = (unsigned short*)(ws + 0);
    unsigned short* hbuf  = (unsigned short*)(ws + 8388608ull);
    unsigned int*   bar   = (unsigned int*)(ws + 9437184ull);
    float* M    = (float*)(ws + 10485760ull);
    float* bE   = (float*)(ws + 10551296ull);
    float* bP   = (float*)(ws + 10567680ull);

    k_wfrag<<<2048, 256, 0, stream>>>(lin_whh, lin_wih, quat_whh, quat_wih, wfrag);
    k_mbias<<<16, 256, 0, stream>>>(lin_wih, quat_wih, lin_enc_w, quat_enc_w,
                                    lin_enc_b, quat_enc_b, lin_bih, lin_bhh,
                                    quat_bih, quat_bhh, M, bE, bP);
    k_zero<<<257, 256, 0, stream>>>((int4*)(ws + 8388608ull));   // hbuf (both parities) + counters
    k_initout<<<3017, 256, 0, stream>>>(out, lin_dec_b, quat_dec_b);

    k_persist<<<256, 256, 0, stream>>>(x, wfrag, M, bE, bP, lin_dec_w, quat_dec_w,
                                       hbuf, out, bar);
}

// Round 4
// 3694.500 us; speedup vs baseline: 2.3466x; 2.3466x over previous
//
#include <hip/hip_runtime.h>

#define BB 256
#define SS 336
#define HH 512
#define NT 431   // output time steps
#define NU 432   // total cell steps (336 enc + 96 pred)

typedef __attribute__((ext_vector_type(8))) short bf16x8;
typedef __attribute__((ext_vector_type(16))) float f32x16;
typedef __attribute__((ext_vector_type(4))) int i32x4;   // native vector: ok for asm "v"

// ---------------- ws layout (bytes) ----------------
// wFrag : 4 matrices (lin_whh, lin_wih, quat_whh, quat_wih), fragment-order bf16
//         each 2048*512*2B = 2 MB                              @ 0
// hbuf  : 2 parity * 2 branch * 8rb*32kb*64lane*8 bf16 (1 MB)  @ 8388608
// bar   : 8 groups * 32 slots * 64 B = 16 KB                   @ 9437184
// M     : [2][2048][4] f32                                     @ 10485760
// bE    : [2][2048] f32                                        @ 10551296
// bP    : [2][2048] f32                                        @ 10567680

__device__ inline unsigned short f2bf(float f) {
    unsigned int u = __float_as_uint(f);
    unsigned int r = (u + 0x7fffu + ((u >> 16) & 1u)) >> 16;
    return (unsigned short)r;
}
__device__ inline float sigm(float x) { return 1.f / (1.f + __expf(-x)); }
__device__ inline float tanh_(float x) { return 2.f / (1.f + __expf(-2.f * x)) - 1.f; }

// LLC-coherent (cross-XCD) 16B load/store: sc0 sc1 bypass L1/L2.
__device__ inline i32x4 llc_load_b128(const i32x4* p) {
    i32x4 r;
    asm volatile("global_load_dwordx4 %0, %1, off sc0 sc1" : "=v"(r) : "v"(p));
    return r;   // NOT ready until vm_drain()!
}
__device__ inline void llc_store_b128(i32x4* p, i32x4 v) {
    asm volatile("global_store_dwordx4 %0, %1, off sc0 sc1" :: "v"(p), "v"(v) : "memory");
}
__device__ inline void vm_drain() { asm volatile("s_waitcnt vmcnt(0)" ::: "memory"); }

// Convert the 4 recurrent weight matrices [2048][512] f32 -> bf16 in MFMA
// B-fragment order: [mat][cg(32)][csub(2)][kb(32)][lane(64)][8]
__global__ void k_wfrag(const float* __restrict__ w0, const float* __restrict__ w1,
                        const float* __restrict__ w2, const float* __restrict__ w3,
                        unsigned short* __restrict__ wfrag) {
    int idx = blockIdx.x * 256 + threadIdx.x;      // 0 .. 524287
    int mat = idx >> 17;
    int t = idx & 131071;
    int lane = t & 63;
    int kb = (t >> 6) & 31;
    int csub = (t >> 11) & 1;
    int cg = t >> 12;                               // 0..31
    const float* W = mat == 0 ? w0 : (mat == 1 ? w1 : (mat == 2 ? w2 : w3));
    int n_local = csub * 32 + (lane & 31);          // local gate-col 0..63
    int n = (n_local >> 4) * 512 + cg * 16 + (n_local & 15);  // global gate row
    int k0 = kb * 16 + (lane >> 5) * 8;
    const float* src = W + n * 512 + k0;
    unsigned short us[8];
#pragma unroll
    for (int j = 0; j < 8; ++j) us[j] = f2bf(src[j]);
    i32x4 v;
    v.x = us[0] | (us[1] << 16); v.y = us[2] | (us[3] << 16);
    v.z = us[4] | (us[5] << 16); v.w = us[6] | (us[7] << 16);
    ((i32x4*)wfrag)[idx] = v;
}

// M = Wih@We  [2][2048][4], bE = Wih@be + bih + bhh, bP = bih + bhh
__global__ void k_mbias(const float* __restrict__ lin_wih, const float* __restrict__ quat_wih,
                        const float* __restrict__ lin_enc_w, const float* __restrict__ quat_enc_w,
                        const float* __restrict__ lin_enc_b, const float* __restrict__ quat_enc_b,
                        const float* __restrict__ lin_bih, const float* __restrict__ lin_bhh,
                        const float* __restrict__ quat_bih, const float* __restrict__ quat_bhh,
                        float* __restrict__ M, float* __restrict__ bE, float* __restrict__ bP) {
    int gid = blockIdx.x * 256 + threadIdx.x;      // 0..4095
    int branch = gid >> 11;
    int n = gid & 2047;
    int nf = 3 + branch;
    const float* Wih = branch ? quat_wih : lin_wih;
    const float* We  = branch ? quat_enc_w : lin_enc_w;
    const float* be  = branch ? quat_enc_b : lin_enc_b;
    const float* bih = branch ? quat_bih : lin_bih;
    const float* bhh = branch ? quat_bhh : lin_bhh;
    float m[4] = {0.f, 0.f, 0.f, 0.f};
    float bs = 0.f;
    for (int j = 0; j < 512; ++j) {
        float w = Wih[n * 512 + j];
#pragma unroll
        for (int kf = 0; kf < 4; ++kf)
            if (kf < nf) m[kf] += w * We[j * nf + kf];
        bs += w * be[j];
    }
    float* Mp = M + (branch * 2048 + n) * 4;
#pragma unroll
    for (int kf = 0; kf < 4; ++kf) Mp[kf] = m[kf];
    bE[branch * 2048 + n] = bs + bih[n] + bhh[n];
    bP[branch * 2048 + n] = bih[n] + bhh[n];
}

__global__ void k_zero(i32x4* __restrict__ p) {
    int idx = blockIdx.x * 256 + threadIdx.x;      // 260 blocks: hbuf (1 MB) + bar (16 KB)
    p[idx] = i32x4{0, 0, 0, 0};
}

__global__ void k_initout(float* __restrict__ out,
                          const float* __restrict__ lb, const float* __restrict__ qb) {
    int idx = blockIdx.x * 256 + threadIdx.x;      // exactly 772352
    if (idx < BB * NT * 7) {
        int d = idx % 7;
        out[idx] = d < 3 ? lb[d] : qb[d - 3];
    }
}

// Persistent kernel: all 432 LSTM steps for both branches.
// 256 blocks x 256 threads, 1 block/CU. blk: branch = blk>>7, rg = (blk>>5)&3, cg = blk&31.
// 8 independent groups of 32 blocks. Sync: fence-free LLC protocol —
// h exchanged via sc0/sc1 (L2-bypass) stores+loads; per-block step flags
// (relaxed agent atomics, no RMW contention); 32-lane parallel poll.
// No cache-maintenance ops anywhere in the loop.
__global__ __launch_bounds__(256, 1) void k_persist(
    const float* __restrict__ x,
    const unsigned short* __restrict__ wfrag,
    const float* __restrict__ M, const float* __restrict__ bE, const float* __restrict__ bP,
    const float* __restrict__ lin_dec_w, const float* __restrict__ quat_dec_w,
    unsigned short* __restrict__ hbuf,
    float* __restrict__ out,
    unsigned int* __restrict__ bar) {
    __shared__ i32x4 lds_a[4096];    // staged A tile: [rsub(2)][kb(32)][lane(64)] i32x4 = 64 KB
    __shared__ float g_lds[64 * 65];
    __shared__ float h_tile[64 * 17];
    __shared__ float mE[256];        // [gate][jj][kf]
    __shared__ float bEs[64];        // [gate][jj]
    __shared__ float bPs[64];
    __shared__ float wds[64];        // [d][j2]

    const int tid = threadIdx.x;
    const int lane = tid & 63;
    const int wv = tid >> 6;
    const int rsub = wv & 1, csub = wv >> 1;
    const int blk = blockIdx.x;
    const int branch = blk >> 7;
    const int rg = (blk >> 5) & 3;
    const int cg = blk & 31;
    const int group = blk >> 5;                 // 0..7
    const int nf = 3 + branch;
    const int row = tid & 63;
    const int jbase = tid >> 6;
    const int b = rg * 64 + row;

    // ---- one-time LDS staging of per-block constants
    {
        int gate = tid >> 6, jj = (tid >> 2) & 15, kf = tid & 3;
        mE[tid] = M[(size_t)(branch * 2048 + gate * 512 + cg * 16 + jj) * 4 + kf];
    }
    if (tid < 64) {
        int gate = tid >> 4, jj = tid & 15;
        bEs[tid] = bE[branch * 2048 + gate * 512 + cg * 16 + jj];
        bPs[tid] = bP[branch * 2048 + gate * 512 + cg * 16 + jj];
        const float* dw = branch ? quat_dec_w : lin_dec_w;
        wds[tid] = (gate < nf) ? dw[gate * 512 + cg * 16 + jj] : 0.f;
    }

    // ---- register-resident weight fragments for this wave (enc matrix first)
    const i32x4* BpE = (const i32x4*)wfrag + (size_t)(branch * 2) * 131072
                       + ((cg * 2 + csub) * 32) * 64 + lane;
    const i32x4* BpP = BpE + 131072;
    i32x4 bw[32];
#pragma unroll
    for (int kb = 0; kb < 32; ++kb) bw[kb] = BpE[kb * 64];

    float creg[4] = {0.f, 0.f, 0.f, 0.f};
    unsigned int* myslot = bar + (size_t)((group << 5) | cg) * 16;   // 64 B spacing

    __syncthreads();

    for (int u = 0; u < NU; ++u) {
        const int is_enc = (u < SS);

        // x loads: read-only, L1/L2-cached (never invalidated), off critical path
        float xv0 = 0.f, xv1 = 0.f, xv2 = 0.f, xv3 = 0.f;
        if (is_enc) {
            const float* xp = x + ((size_t)b * SS + u) * 7 + branch * 3;
            xv0 = xp[0]; xv1 = xp[1]; xv2 = xp[2];
            if (branch) xv3 = xp[3];
        }
        if (u == SS) {      // enc -> pred weight switch (Whh -> Wih)
#pragma unroll
            for (int kb = 0; kb < 32; ++kb) bw[kb] = BpP[kb * 64];
        }

        // ---- group barrier: 32 lanes poll the 32 peer flags in parallel
        if (u > 0) {
            if (tid < 64) {
                unsigned int* slot = bar + (size_t)((group << 5) | (lane & 31)) * 16;
                while (!__all((int)(__hip_atomic_load(slot, __ATOMIC_RELAXED,
                                                      __HIP_MEMORY_SCOPE_AGENT)
                                    >= (unsigned int)u)))
                    __builtin_amdgcn_s_sleep(2);
            }
            __syncthreads();
        }

        // ---- stage A tile (64 rows x 512 h, bf16 fragments) LLC -> LDS, coalesced
        {
            const i32x4* gsrc = (const i32x4*)hbuf + (size_t)(u & 1) * 32768
                                + (size_t)branch * 16384 + rg * 4096 + tid;
            i32x4 av[16];
#pragma unroll
            for (int i = 0; i < 16; ++i) av[i] = llc_load_b128(gsrc + i * 256);
            vm_drain();
            __builtin_amdgcn_sched_barrier(0);
#pragma unroll
            for (int i = 0; i < 16; ++i) lds_a[i * 256 + tid] = av[i];
        }
        __syncthreads();

        // ---- GEMM: g[64 x 64] = h[64 x 512] @ W_sliceT; A from LDS, B from registers
        f32x16 acc0 = {};
        f32x16 acc1 = {};
        const i32x4* Afrag = lds_a + rsub * 2048 + lane;
#pragma unroll
        for (int kb = 0; kb < 32; kb += 2) {
            i32x4 a0 = Afrag[kb * 64];
            i32x4 a1 = Afrag[(kb + 1) * 64];
            acc0 = __builtin_amdgcn_mfma_f32_32x32x16_bf16(*(const bf16x8*)&a0, *(const bf16x8*)&bw[kb], acc0, 0, 0, 0);
            acc1 = __builtin_amdgcn_mfma_f32_32x32x16_bf16(*(const bf16x8*)&a1, *(const bf16x8*)&bw[kb + 1], acc1, 0, 0, 0);
        }
        // C layout (32x32): col = lane&31, row = (reg&3) + 8*(reg>>2) + 4*(lane>>5)
        int col_l = csub * 32 + (lane & 31);
        int rbase = rsub * 32 + 4 * (lane >> 5);
#pragma unroll
        for (int r = 0; r < 16; ++r) {
            int row_l = rbase + (r & 3) + 8 * (r >> 2);
            g_lds[row_l * 65 + col_l] = acc0[r] + acc1[r];
        }
        __syncthreads();

        // ---- gates: thread handles row, jj = jbase*4 + p
#pragma unroll
        for (int p = 0; p < 4; ++p) {
            int jj = jbase * 4 + p;
            float gi = g_lds[row * 65 + jj];
            float gf = g_lds[row * 65 + 16 + jj];
            float gc = g_lds[row * 65 + 32 + jj];
            float go = g_lds[row * 65 + 48 + jj];
            if (is_enc) {
                int j4 = jj * 4;
                gi += bEs[jj]      + xv0 * mE[j4]       + xv1 * mE[j4 + 1]       + xv2 * mE[j4 + 2]       + xv3 * mE[j4 + 3];
                gf += bEs[16 + jj] + xv0 * mE[64 + j4]  + xv1 * mE[64 + j4 + 1]  + xv2 * mE[64 + j4 + 2]  + xv3 * mE[64 + j4 + 3];
                gc += bEs[32 + jj] + xv0 * mE[128 + j4] + xv1 * mE[128 + j4 + 1] + xv2 * mE[128 + j4 + 2] + xv3 * mE[128 + j4 + 3];
                go += bEs[48 + jj] + xv0 * mE[192 + j4] + xv1 * mE[192 + j4 + 1] + xv2 * mE[192 + j4 + 2] + xv3 * mE[192 + j4 + 3];
            } else {
                gi += bPs[jj];
                gf += bPs[16 + jj];
                gc += bPs[32 + jj];
                go += bPs[48 + jj];
            }
            float iv = sigm(gi), fv = sigm(gf), gv = tanh_(gc), ov = sigm(go);
            float cn;
            if (is_enc) {
                cn = fv * creg[p] + iv * gv;
                creg[p] = cn;
            } else {
                cn = iv * gv;   // pred steps start from zero state
            }
            h_tile[row * 17 + jj] = ov * tanh_(cn);
        }
        __syncthreads();

        // ---- write h_new (bf16, fragment order) to LLC for the group
        if (tid < 128) {
            int chunk = tid >> 6;
            int l = tid & 63;
            int row_l = chunk * 32 + (l & 31);
            int jh = (l >> 5) * 8;
            unsigned short us[8];
#pragma unroll
            for (int j = 0; j < 8; ++j) us[j] = f2bf(h_tile[row_l * 17 + jh + j]);
            i32x4 v;
            v.x = us[0] | (us[1] << 16); v.y = us[2] | (us[3] << 16);
            v.z = us[4] | (us[5] << 16); v.w = us[6] | (us[7] << 16);
            int rb = rg * 2 + chunk;
            llc_store_b128((i32x4*)hbuf + (size_t)((u + 1) & 1) * 32768
                           + (size_t)branch * 16384 + (rb * 32 + cg) * 64 + l, v);
        }
        vm_drain();          // h-stores ACKed at LLC before the flag can be written
        __syncthreads();

        // ---- arrive: publish step completion (no fence, no RMW contention)
        if (tid == 0)
            __hip_atomic_store(myslot, (unsigned int)(u + 1), __ATOMIC_RELAXED,
                               __HIP_MEMORY_SCOPE_AGENT);

        // ---- fused decoder (off the critical path, after arrive)
        if (u >= 1) {
            if (jbase < nf) {
                float s = 0.f;
#pragma unroll
                for (int j2 = 0; j2 < 16; ++j2) s += h_tile[row * 17 + j2] * wds[jbase * 16 + j2];
                unsafeAtomicAdd(out + ((size_t)b * NT + (u - 1)) * 7 + branch * 3 + jbase, s);
            }
        }
    }
}

extern "C" void kernel_launch(void* const* d_in, const int* in_sizes, int n_in,
                              void* d_out, int out_size, void* d_ws, size_t ws_size,
                              hipStream_t stream) {
    const float* x          = (const float*)d_in[0];
    const float* lin_enc_w  = (const float*)d_in[1];
    const float* lin_enc_b  = (const float*)d_in[2];
    const float* quat_enc_w = (const float*)d_in[3];
    const float* quat_enc_b = (const float*)d_in[4];
    const float* lin_wih    = (const float*)d_in[5];
    const float* lin_whh    = (const float*)d_in[6];
    const float* lin_bih    = (const float*)d_in[7];
    const float* lin_bhh    = (const float*)d_in[8];
    const float* quat_wih   = (const float*)d_in[9];
    const float* quat_whh   = (const float*)d_in[10];
    const float* quat_bih   = (const float*)d_in[11];
    const float* quat_bhh   = (const float*)d_in[12];
    const float* lin_dec_w  = (const float*)d_in[13];
    const float* lin_dec_b  = (const float*)d_in[14];
    const float* quat_dec_w = (const float*)d_in[15];
    const float* quat_dec_b = (const float*)d_in[16];
    float* out = (float*)d_out;
    char* ws = (char*)d_ws;

    unsigned short* wfrag = (unsigned short*)(ws + 0);
    unsigned short* hbuf  = (unsigned short*)(ws + 8388608ull);
    unsigned int*   bar   = (unsigned int*)(ws + 9437184ull);
    float* M    = (float*)(ws + 10485760ull);
    float* bE   = (float*)(ws + 10551296ull);
    float* bP   = (float*)(ws + 10567680ull);

    k_wfrag<<<2048, 256, 0, stream>>>(lin_whh, lin_wih, quat_whh, quat_wih, wfrag);
    k_mbias<<<16, 256, 0, stream>>>(lin_wih, quat_wih, lin_enc_w, quat_enc_w,
                                    lin_enc_b, quat_enc_b, lin_bih, lin_bhh,
                                    quat_bih, quat_bhh, M, bE, bP);
    k_zero<<<260, 256, 0, stream>>>((i32x4*)(ws + 8388608ull));   // hbuf + bar (flags)
    k_initout<<<3017, 256, 0, stream>>>(out, lin_dec_b, quat_dec_b);

    k_persist<<<256, 256, 0, stream>>>(x, wfrag, M, bE, bP, lin_dec_w, quat_dec_w,
                                       hbuf, out, bar);
}

// Round 5
// 3592.345 us; speedup vs baseline: 2.4134x; 1.0284x over previous
//
#include <hip/hip_runtime.h>

#define BB 256
#define SS 336
#define HH 512
#define NT 431   // output time steps
#define NU 432   // total cell steps (336 enc + 96 pred)

typedef __attribute__((ext_vector_type(8))) short bf16x8;
typedef __attribute__((ext_vector_type(16))) float f32x16;
typedef __attribute__((ext_vector_type(4))) int i32x4;   // native vector: ok for asm "v"

// ---------------- ws layout (bytes) ----------------
// wFrag : 4 matrices (lin_whh, lin_wih, quat_whh, quat_wih), fragment-order bf16
//         each 2048*512*2B = 2 MB                              @ 0
// hbuf  : 2 parity * 2 branch * 8rb*32kb*64lane*8 bf16 (1 MB)  @ 8388608
// bar   : 8 groups * 32 slots * 64 B = 16 KB                   @ 9437184
// M     : [2][2048][4] f32                                     @ 10485760
// bE    : [2][2048] f32                                        @ 10551296
// bP    : [2][2048] f32                                        @ 10567680

__device__ inline unsigned short f2bf(float f) {
    unsigned int u = __float_as_uint(f);
    unsigned int r = (u + 0x7fffu + ((u >> 16) & 1u)) >> 16;
    return (unsigned short)r;
}
__device__ inline float sigm(float x) { return 1.f / (1.f + __expf(-x)); }
__device__ inline float tanh_(float x) { return 2.f / (1.f + __expf(-2.f * x)) - 1.f; }

// LLC-coherent (cross-XCD) 16B load/store: sc0 sc1 bypass L1/L2.
__device__ inline i32x4 llc_load_b128(const i32x4* p) {
    i32x4 r;
    asm volatile("global_load_dwordx4 %0, %1, off sc0 sc1" : "=v"(r) : "v"(p));
    return r;   // NOT ready until vm_drain()!
}
__device__ inline void llc_store_b128(i32x4* p, i32x4 v) {
    asm volatile("global_store_dwordx4 %0, %1, off sc0 sc1" :: "v"(p), "v"(v) : "memory");
}
__device__ inline void vm_drain() { asm volatile("s_waitcnt vmcnt(0)" ::: "memory"); }

// Convert the 4 recurrent weight matrices [2048][512] f32 -> bf16 in MFMA
// B-fragment order: [mat][cg(32)][csub(2)][kb(32)][lane(64)][8]
__global__ void k_wfrag(const float* __restrict__ w0, const float* __restrict__ w1,
                        const float* __restrict__ w2, const float* __restrict__ w3,
                        unsigned short* __restrict__ wfrag) {
    int idx = blockIdx.x * 256 + threadIdx.x;      // 0 .. 524287
    int mat = idx >> 17;
    int t = idx & 131071;
    int lane = t & 63;
    int kb = (t >> 6) & 31;
    int csub = (t >> 11) & 1;
    int cg = t >> 12;                               // 0..31
    const float* W = mat == 0 ? w0 : (mat == 1 ? w1 : (mat == 2 ? w2 : w3));
    int n_local = csub * 32 + (lane & 31);          // local gate-col 0..63
    int n = (n_local >> 4) * 512 + cg * 16 + (n_local & 15);  // global gate row
    int k0 = kb * 16 + (lane >> 5) * 8;
    const float* src = W + n * 512 + k0;
    unsigned short us[8];
#pragma unroll
    for (int j = 0; j < 8; ++j) us[j] = f2bf(src[j]);
    i32x4 v;
    v.x = us[0] | (us[1] << 16); v.y = us[2] | (us[3] << 16);
    v.z = us[4] | (us[5] << 16); v.w = us[6] | (us[7] << 16);
    ((i32x4*)wfrag)[idx] = v;
}

// M = Wih@We  [2][2048][4], bE = Wih@be + bih + bhh, bP = bih + bhh
__global__ void k_mbias(const float* __restrict__ lin_wih, const float* __restrict__ quat_wih,
                        const float* __restrict__ lin_enc_w, const float* __restrict__ quat_enc_w,
                        const float* __restrict__ lin_enc_b, const float* __restrict__ quat_enc_b,
                        const float* __restrict__ lin_bih, const float* __restrict__ lin_bhh,
                        const float* __restrict__ quat_bih, const float* __restrict__ quat_bhh,
                        float* __restrict__ M, float* __restrict__ bE, float* __restrict__ bP) {
    int gid = blockIdx.x * 256 + threadIdx.x;      // 0..4095
    int branch = gid >> 11;
    int n = gid & 2047;
    int nf = 3 + branch;
    const float* Wih = branch ? quat_wih : lin_wih;
    const float* We  = branch ? quat_enc_w : lin_enc_w;
    const float* be  = branch ? quat_enc_b : lin_enc_b;
    const float* bih = branch ? quat_bih : lin_bih;
    const float* bhh = branch ? quat_bhh : lin_bhh;
    float m[4] = {0.f, 0.f, 0.f, 0.f};
    float bs = 0.f;
    for (int j = 0; j < 512; ++j) {
        float w = Wih[n * 512 + j];
#pragma unroll
        for (int kf = 0; kf < 4; ++kf)
            if (kf < nf) m[kf] += w * We[j * nf + kf];
        bs += w * be[j];
    }
    float* Mp = M + (branch * 2048 + n) * 4;
#pragma unroll
    for (int kf = 0; kf < 4; ++kf) Mp[kf] = m[kf];
    bE[branch * 2048 + n] = bs + bih[n] + bhh[n];
    bP[branch * 2048 + n] = bih[n] + bhh[n];
}

__global__ void k_zero(i32x4* __restrict__ p) {
    int idx = blockIdx.x * 256 + threadIdx.x;      // 260 blocks: hbuf (1 MB) + bar (16 KB)
    p[idx] = i32x4{0, 0, 0, 0};
}

// Persistent kernel: all 432 LSTM steps for both branches.
// 256 blocks x 256 threads, 1 block/CU. blk: branch = blk>>7, rg = (blk>>5)&3, cg = blk&31.
// 8 independent groups of 32 blocks. Sync: fence-free LLC protocol —
// h exchanged via sc0/sc1 (L2-bypass) stores+loads; per-block step flags
// (relaxed agent atomics); 32-lane parallel poll. No atomics on out:
// each block decodes rows {2cg,2cg+1} from its full staged h in lds_a
// (complete 512-dot, single writer, plain store). Loop runs NU+1 times;
// the extra iteration decodes the final h.
__global__ __launch_bounds__(256, 1) void k_persist(
    const float* __restrict__ x,
    const unsigned short* __restrict__ wfrag,
    const float* __restrict__ M, const float* __restrict__ bE, const float* __restrict__ bP,
    const float* __restrict__ lin_dec_w, const float* __restrict__ quat_dec_w,
    const float* __restrict__ lin_dec_b, const float* __restrict__ quat_dec_b,
    unsigned short* __restrict__ hbuf,
    float* __restrict__ out,
    unsigned int* __restrict__ bar) {
    __shared__ i32x4 lds_a[4096];    // staged A tile: [chunk(2)][cg_w(32)][lane(64)] i32x4 = 64 KB
    __shared__ float g_lds[64 * 65];
    __shared__ float h_tile[64 * 17];
    __shared__ float mE[256];        // [gate][jj][kf]
    __shared__ float bEs[64];        // [gate][jj]
    __shared__ float bPs[64];

    const int tid = threadIdx.x;
    const int lane = tid & 63;
    const int wv = tid >> 6;
    const int rsub = wv & 1, csub = wv >> 1;
    const int blk = blockIdx.x;
    const int branch = blk >> 7;
    const int rg = (blk >> 5) & 3;
    const int cg = blk & 31;
    const int group = blk >> 5;                 // 0..7
    const int nf = 3 + branch;
    const int row = tid & 63;
    const int jbase = tid >> 6;
    const int b = rg * 64 + row;

    // ---- one-time LDS staging of per-block constants
    {
        int gate = tid >> 6, jj = (tid >> 2) & 15, kf = tid & 3;
        mE[tid] = M[(size_t)(branch * 2048 + gate * 512 + cg * 16 + jj) * 4 + kf];
    }
    if (tid < 64) {
        int gate = tid >> 4, jj = tid & 15;
        bEs[tid] = bE[branch * 2048 + gate * 512 + cg * 16 + jj];
        bPs[tid] = bP[branch * 2048 + gate * 512 + cg * 16 + jj];
    }

    // ---- decoder role (wave 0 only): lane -> (row-pair member, dim, k-segment)
    const int dr   = lane & 1;                  // 0/1 -> row 2cg+dr
    const int dd   = (lane >> 1) & 3;           // decoder output dim
    const int dseg = lane >> 3;                 // 0..7, 64-wide k segment
    const int drow = cg * 2 + dr;               // row within this rg's 64-row slice
    const bool dvalid = dd < nf;
    const float* dwp = (branch ? quat_dec_w : lin_dec_w) + dd * 512;
    const float dbias = dvalid ? (branch ? quat_dec_b : lin_dec_b)[dd] : 0.f;

    // ---- register-resident weight fragments for this wave (enc matrix first)
    const i32x4* BpE = (const i32x4*)wfrag + (size_t)(branch * 2) * 131072
                       + ((cg * 2 + csub) * 32) * 64 + lane;
    const i32x4* BpP = BpE + 131072;
    i32x4 bw[32];
#pragma unroll
    for (int kb = 0; kb < 32; ++kb) bw[kb] = BpE[kb * 64];

    float creg[4] = {0.f, 0.f, 0.f, 0.f};
    unsigned int* myslot = bar + (size_t)((group << 5) | cg) * 16;   // 64 B spacing

    __syncthreads();

    for (int u = 0; u <= NU; ++u) {
        const int is_enc = (u < SS);

        // x loads: read-only, L1/L2-cached (never invalidated), off critical path
        float xv0 = 0.f, xv1 = 0.f, xv2 = 0.f, xv3 = 0.f;
        if (is_enc) {
            const float* xp = x + ((size_t)b * SS + u) * 7 + branch * 3;
            xv0 = xp[0]; xv1 = xp[1]; xv2 = xp[2];
            if (branch) xv3 = xp[3];
        }
        if (u == SS) {      // enc -> pred weight switch (Whh -> Wih)
#pragma unroll
            for (int kb = 0; kb < 32; ++kb) bw[kb] = BpP[kb * 64];
        }

        // ---- group barrier: 32 lanes poll the 32 peer flags in parallel
        if (u > 0) {
            if (tid < 64) {
                unsigned int* slot = bar + (size_t)((group << 5) | (lane & 31)) * 16;
                while (!__all((int)(__hip_atomic_load(slot, __ATOMIC_RELAXED,
                                                      __HIP_MEMORY_SCOPE_AGENT)
                                    >= (unsigned int)u)))
                    __builtin_amdgcn_s_sleep(2);
            }
            __syncthreads();
        }

        // ---- stage A tile (64 rows x 512 h, bf16 fragments) LLC -> LDS, coalesced
        {
            const i32x4* gsrc = (const i32x4*)hbuf + (size_t)(u & 1) * 32768
                                + (size_t)branch * 16384 + rg * 4096 + tid;
            i32x4 av[16];
#pragma unroll
            for (int i = 0; i < 16; ++i) av[i] = llc_load_b128(gsrc + i * 256);
            vm_drain();
            __builtin_amdgcn_sched_barrier(0);
#pragma unroll
            for (int i = 0; i < 16; ++i) lds_a[i * 256 + tid] = av[i];
        }
        __syncthreads();

        if (u == NU) {      // final iteration: only decode h_{NU-1} -> t = NU-2
            if (wv == 0) {
                float s = 0.f;
                if (dvalid) {
                    const unsigned short* hp = (const unsigned short*)lds_a;
                    int rowb = (drow >> 5) * 16384 + (drow & 31) * 8;
#pragma unroll
                    for (int jj = 0; jj < 64; ++jj) {
                        int j = dseg * 64 + jj;
                        unsigned short hu = hp[rowb + (j >> 4) * 512 + ((j >> 3) & 1) * 256 + (j & 7)];
                        s += __uint_as_float(((unsigned int)hu) << 16) * dwp[j];
                    }
                }
                s += __shfl_xor(s, 8);
                s += __shfl_xor(s, 16);
                s += __shfl_xor(s, 32);
                if (dseg == 0 && dvalid)
                    out[((size_t)(rg * 64 + drow) * NT + (u - 2)) * 7 + branch * 3 + dd] = s + dbias;
            }
            break;
        }

        // ---- GEMM: g[64 x 64] = h[64 x 512] @ W_sliceT; A from LDS, B from registers
        f32x16 acc0 = {};
        f32x16 acc1 = {};
        const i32x4* Afrag = lds_a + rsub * 2048 + lane;
#pragma unroll
        for (int kb = 0; kb < 32; kb += 2) {
            i32x4 a0 = Afrag[kb * 64];
            i32x4 a1 = Afrag[(kb + 1) * 64];
            acc0 = __builtin_amdgcn_mfma_f32_32x32x16_bf16(*(const bf16x8*)&a0, *(const bf16x8*)&bw[kb], acc0, 0, 0, 0);
            acc1 = __builtin_amdgcn_mfma_f32_32x32x16_bf16(*(const bf16x8*)&a1, *(const bf16x8*)&bw[kb + 1], acc1, 0, 0, 0);
        }
        // C layout (32x32): col = lane&31, row = (reg&3) + 8*(reg>>2) + 4*(lane>>5)
        int col_l = csub * 32 + (lane & 31);
        int rbase = rsub * 32 + 4 * (lane >> 5);
#pragma unroll
        for (int r = 0; r < 16; ++r) {
            int row_l = rbase + (r & 3) + 8 * (r >> 2);
            g_lds[row_l * 65 + col_l] = acc0[r] + acc1[r];
        }
        __syncthreads();

        // ---- gates: thread handles row, jj = jbase*4 + p
#pragma unroll
        for (int p = 0; p < 4; ++p) {
            int jj = jbase * 4 + p;
            float gi = g_lds[row * 65 + jj];
            float gf = g_lds[row * 65 + 16 + jj];
            float gc = g_lds[row * 65 + 32 + jj];
            float go = g_lds[row * 65 + 48 + jj];
            if (is_enc) {
                int j4 = jj * 4;
                gi += bEs[jj]      + xv0 * mE[j4]       + xv1 * mE[j4 + 1]       + xv2 * mE[j4 + 2]       + xv3 * mE[j4 + 3];
                gf += bEs[16 + jj] + xv0 * mE[64 + j4]  + xv1 * mE[64 + j4 + 1]  + xv2 * mE[64 + j4 + 2]  + xv3 * mE[64 + j4 + 3];
                gc += bEs[32 + jj] + xv0 * mE[128 + j4] + xv1 * mE[128 + j4 + 1] + xv2 * mE[128 + j4 + 2] + xv3 * mE[128 + j4 + 3];
                go += bEs[48 + jj] + xv0 * mE[192 + j4] + xv1 * mE[192 + j4 + 1] + xv2 * mE[192 + j4 + 2] + xv3 * mE[192 + j4 + 3];
            } else {
                gi += bPs[jj];
                gf += bPs[16 + jj];
                gc += bPs[32 + jj];
                go += bPs[48 + jj];
            }
            float iv = sigm(gi), fv = sigm(gf), gv = tanh_(gc), ov = sigm(go);
            float cn;
            if (is_enc) {
                cn = fv * creg[p] + iv * gv;
                creg[p] = cn;
            } else {
                cn = iv * gv;   // pred steps start from zero state
            }
            h_tile[row * 17 + jj] = ov * tanh_(cn);
        }
        __syncthreads();

        // ---- write h_new (bf16, fragment order) to LLC for the group
        if (tid < 128) {
            int chunk = tid >> 6;
            int l = tid & 63;
            int row_l = chunk * 32 + (l & 31);
            int jh = (l >> 5) * 8;
            unsigned short us[8];
#pragma unroll
            for (int j = 0; j < 8; ++j) us[j] = f2bf(h_tile[row_l * 17 + jh + j]);
            i32x4 v;
            v.x = us[0] | (us[1] << 16); v.y = us[2] | (us[3] << 16);
            v.z = us[4] | (us[5] << 16); v.w = us[6] | (us[7] << 16);
            int rb = rg * 2 + chunk;
            llc_store_b128((i32x4*)hbuf + (size_t)((u + 1) & 1) * 32768
                           + (size_t)branch * 16384 + (rb * 32 + cg) * 64 + l, v);
        }
        vm_drain();          // h-stores ACKed at LLC before the flag can be written
        __syncthreads();

        // ---- arrive: publish step completion (no fence, no RMW contention)
        if (tid == 0)
            __hip_atomic_store(myslot, (unsigned int)(u + 1), __ATOMIC_RELAXED,
                               __HIP_MEMORY_SCOPE_AGENT);

        // ---- decode h_{u-1} (full 512-dot from lds_a), off the critical path
        if (u >= 2 && wv == 0) {
            float s = 0.f;
            if (dvalid) {
                const unsigned short* hp = (const unsigned short*)lds_a;
                int rowb = (drow >> 5) * 16384 + (drow & 31) * 8;
#pragma unroll
                for (int jj = 0; jj < 64; ++jj) {
                    int j = dseg * 64 + jj;
                    unsigned short hu = hp[rowb + (j >> 4) * 512 + ((j >> 3) & 1) * 256 + (j & 7)];
                    s += __uint_as_float(((unsigned int)hu) << 16) * dwp[j];
                }
            }
            s += __shfl_xor(s, 8);
            s += __shfl_xor(s, 16);
            s += __shfl_xor(s, 32);
            if (dseg == 0 && dvalid)
                out[((size_t)(rg * 64 + drow) * NT + (u - 2)) * 7 + branch * 3 + dd] = s + dbias;
        }
    }
}

extern "C" void kernel_launch(void* const* d_in, const int* in_sizes, int n_in,
                              void* d_out, int out_size, void* d_ws, size_t ws_size,
                              hipStream_t stream) {
    const float* x          = (const float*)d_in[0];
    const float* lin_enc_w  = (const float*)d_in[1];
    const float* lin_enc_b  = (const float*)d_in[2];
    const float* quat_enc_w = (const float*)d_in[3];
    const float* quat_enc_b = (const float*)d_in[4];
    const float* lin_wih    = (const float*)d_in[5];
    const float* lin_whh    = (const float*)d_in[6];
    const float* lin_bih    = (const float*)d_in[7];
    const float* lin_bhh    = (const float*)d_in[8];
    const float* quat_wih   = (const float*)d_in[9];
    const float* quat_whh   = (const float*)d_in[10];
    const float* quat_bih   = (const float*)d_in[11];
    const float* quat_bhh   = (const float*)d_in[12];
    const float* lin_dec_w  = (const float*)d_in[13];
    const float* lin_dec_b  = (const float*)d_in[14];
    const float* quat_dec_w = (const float*)d_in[15];
    const float* quat_dec_b = (const float*)d_in[16];
    float* out = (float*)d_out;
    char* ws = (char*)d_ws;

    unsigned short* wfrag = (unsigned short*)(ws + 0);
    unsigned short* hbuf  = (unsigned short*)(ws + 8388608ull);
    unsigned int*   bar   = (unsigned int*)(ws + 9437184ull);
    float* M    = (float*)(ws + 10485760ull);
    float* bE   = (float*)(ws + 10551296ull);
    float* bP   = (float*)(ws + 10567680ull);

    k_wfrag<<<2048, 256, 0, stream>>>(lin_whh, lin_wih, quat_whh, quat_wih, wfrag);
    k_mbias<<<16, 256, 0, stream>>>(lin_wih, quat_wih, lin_enc_w, quat_enc_w,
                                    lin_enc_b, quat_enc_b, lin_bih, lin_bhh,
                                    quat_bih, quat_bhh, M, bE, bP);
    k_zero<<<260, 256, 0, stream>>>((i32x4*)(ws + 8388608ull));   // hbuf + bar (flags)

    k_persist<<<256, 256, 0, stream>>>(x, wfrag, M, bE, bP, lin_dec_w, quat_dec_w,
                                       lin_dec_b, quat_dec_b, hbuf, out, bar);
}

// Round 8
// 2996.546 us; speedup vs baseline: 2.8932x; 1.1988x over previous
//
#include <hip/hip_runtime.h>

#define BB 256
#define SS 336
#define HH 512
#define NT 431   // output time steps
#define NU 432   // total cell steps (336 enc + 96 pred)

typedef __attribute__((ext_vector_type(8))) short bf16x8;
typedef __attribute__((ext_vector_type(16))) float f32x16;
typedef __attribute__((ext_vector_type(4))) int i32x4;   // native vector: ok for asm "v"

// ---------------- ws layout (bytes) ----------------
// wFrag : 4 matrices (lin_whh, lin_wih, quat_whh, quat_wih), fragment-order bf16
//         each 2048*512*2B = 2 MB                              @ 0
//         order per mat: [cg(16)][gate-wave(4)][kb(32)][lane(64)][8]
// hbuf  : 2 parity * 2 branch * 8rg*32kb*64lane*8 bf16 (1 MB)  @ 8388608
// bar   : 16 groups * 16 slots * 64 B = 16 KB                  @ 9437184
// M     : [2][2048][4] f32                                     @ 10485760
// bE    : [2][2048] f32                                        @ 10551296
// bP    : [2][2048] f32                                        @ 10567680

__device__ inline unsigned short f2bf(float f) {
    unsigned int u = __float_as_uint(f);
    unsigned int r = (u + 0x7fffu + ((u >> 16) & 1u)) >> 16;
    return (unsigned short)r;
}
__device__ inline float sigm(float x) { return 1.f / (1.f + __expf(-x)); }
__device__ inline float tanh_(float x) { return 2.f / (1.f + __expf(-2.f * x)) - 1.f; }

// LLC-coherent (cross-XCD) 16B load/store: sc0 sc1 bypass L1/L2.
__device__ inline i32x4 llc_load_b128(const i32x4* p) {
    i32x4 r;
    asm volatile("global_load_dwordx4 %0, %1, off sc0 sc1" : "=v"(r) : "v"(p));
    return r;   // NOT ready until vm_drain()!
}
__device__ inline void llc_store_b128(i32x4* p, i32x4 v) {
    asm volatile("global_store_dwordx4 %0, %1, off sc0 sc1" :: "v"(p), "v"(v) : "memory");
}
__device__ inline void vm_drain() { asm volatile("s_waitcnt vmcnt(0)" ::: "memory"); }

// Convert the 4 recurrent weight matrices [2048][512] f32 -> bf16 in MFMA
// B-fragment order: [mat][cg(16)][wq(4)][kb(32)][lane(64)][8]
// wave wq handles gate wq; its 32 cols are n = wq*512 + cg*32 + (lane&31).
__global__ void k_wfrag(const float* __restrict__ w0, const float* __restrict__ w1,
                        const float* __restrict__ w2, const float* __restrict__ w3,
                        unsigned short* __restrict__ wfrag) {
    int idx = blockIdx.x * 256 + threadIdx.x;      // 0 .. 524287
    int mat = idx >> 17;
    int t = idx & 131071;
    int lane = t & 63;
    int kb = (t >> 6) & 31;
    int wq = (t >> 11) & 3;
    int cg = t >> 13;                               // 0..15
    const float* W = mat == 0 ? w0 : (mat == 1 ? w1 : (mat == 2 ? w2 : w3));
    int n = wq * 512 + cg * 32 + (lane & 31);       // global gate row
    int k0 = kb * 16 + (lane >> 5) * 8;
    const float* src = W + n * 512 + k0;
    unsigned short us[8];
#pragma unroll
    for (int j = 0; j < 8; ++j) us[j] = f2bf(src[j]);
    i32x4 v;
    v.x = us[0] | (us[1] << 16); v.y = us[2] | (us[3] << 16);
    v.z = us[4] | (us[5] << 16); v.w = us[6] | (us[7] << 16);
    ((i32x4*)wfrag)[idx] = v;
}

// M = Wih@We  [2][2048][4], bE = Wih@be + bih + bhh, bP = bih + bhh
__global__ void k_mbias(const float* __restrict__ lin_wih, const float* __restrict__ quat_wih,
                        const float* __restrict__ lin_enc_w, const float* __restrict__ quat_enc_w,
                        const float* __restrict__ lin_enc_b, const float* __restrict__ quat_enc_b,
                        const float* __restrict__ lin_bih, const float* __restrict__ lin_bhh,
                        const float* __restrict__ quat_bih, const float* __restrict__ quat_bhh,
                        float* __restrict__ M, float* __restrict__ bE, float* __restrict__ bP) {
    int gid = blockIdx.x * 256 + threadIdx.x;      // 0..4095
    int branch = gid >> 11;
    int n = gid & 2047;
    int nf = 3 + branch;
    const float* Wih = branch ? quat_wih : lin_wih;
    const float* We  = branch ? quat_enc_w : lin_enc_w;
    const float* be  = branch ? quat_enc_b : lin_enc_b;
    const float* bih = branch ? quat_bih : lin_bih;
    const float* bhh = branch ? quat_bhh : lin_bhh;
    float m[4] = {0.f, 0.f, 0.f, 0.f};
    float bs = 0.f;
    for (int j = 0; j < 512; ++j) {
        float w = Wih[n * 512 + j];
#pragma unroll
        for (int kf = 0; kf < 4; ++kf)
            if (kf < nf) m[kf] += w * We[j * nf + kf];
        bs += w * be[j];
    }
    float* Mp = M + (branch * 2048 + n) * 4;
#pragma unroll
    for (int kf = 0; kf < 4; ++kf) Mp[kf] = m[kf];
    bE[branch * 2048 + n] = bs + bih[n] + bhh[n];
    bP[branch * 2048 + n] = bih[n] + bhh[n];
}

__global__ void k_zero(i32x4* __restrict__ p) {
    int idx = blockIdx.x * 256 + threadIdx.x;      // 260 blocks: hbuf (1 MB) + bar (16 KB)
    p[idx] = i32x4{0, 0, 0, 0};
}

// Persistent kernel: all 432 LSTM steps for both branches.
// 256 blocks x 256 threads, 1 block/CU (89.7 KB LDS).
// Tiling: blk -> branch = blk>>7, rg = (blk>>4)&7 (32 rows), cg = blk&15 (128 gatecols).
// group = blk>>4: 16 independent groups of 16 blocks (share the 32-row h slice).
// Groups are by blockIdx => ANY placement is correct (partial residency merely
// serializes; no deadlock). h exchanged via sc0/sc1 LLC ops; per-block step
// flags, 16-lane parallel poll; no fences, no cache maintenance in the loop.
__global__ __launch_bounds__(256, 1) void k_persist(
    const float* __restrict__ x,
    const unsigned short* __restrict__ wfrag,
    const float* __restrict__ M, const float* __restrict__ bE, const float* __restrict__ bP,
    const float* __restrict__ lin_dec_w, const float* __restrict__ quat_dec_w,
    const float* __restrict__ lin_dec_b, const float* __restrict__ quat_dec_b,
    unsigned short* __restrict__ hbuf,
    float* __restrict__ out,
    unsigned int* __restrict__ bar) {
    __shared__ i32x4 lds_a[2][2048];   // staged A tile, double-buffered: 2 x 32 KB
    __shared__ float g_lds[32 * 132];  // 32 rows x 128 gatecols (+4 pad)
    __shared__ float h_tile[32 * 33];  // 32 rows x 32 h-cols (+1 pad)
    __shared__ float mE[512];          // [gate(4)][jj(32)][kf(4)]
    __shared__ float bEs[128];         // [gate(4)][jj(32)]
    __shared__ float bPs[128];

    const int tid = threadIdx.x;
    const int lane = tid & 63;
    const int wv = tid >> 6;           // wave = gate for the GEMM B operand
    const int blk = blockIdx.x;
    const int branch = blk >> 7;
    const int rg = (blk >> 4) & 7;     // 8 row-groups of 32 rows
    const int cg = blk & 15;           // 16 col-groups of 32 h-cols
    const int group = blk >> 4;        // 0..15
    const int nf = 3 + branch;
    const int row = tid & 31;
    const int jbase = tid >> 5;        // 0..7
    const int b = rg * 32 + row;

    // ---- one-time LDS staging of per-block constants
    for (int t = tid; t < 512; t += 256) {
        int gate = t >> 7, jj = (t >> 2) & 31, kf = t & 3;
        mE[t] = M[(size_t)(branch * 2048 + gate * 512 + cg * 32 + jj) * 4 + kf];
    }
    if (tid < 128) {
        int gate = tid >> 5, jj = tid & 31;
        bEs[tid] = bE[branch * 2048 + gate * 512 + cg * 32 + jj];
        bPs[tid] = bP[branch * 2048 + gate * 512 + cg * 32 + jj];
    }

    // ---- decoder role (wave 3): lane -> (row-pair member, dim, k-segment)
    const int dr   = lane & 1;                  // 0/1 -> row 2cg+dr
    const int dd   = (lane >> 1) & 3;           // decoder output dim
    const int dseg = lane >> 3;                 // 0..7, 64-wide k segment
    const int drow = cg * 2 + dr;               // row within this rg's 32-row slice
    const bool dvalid = dd < nf;
    const float* dwp = (branch ? quat_dec_w : lin_dec_w) + dd * 512;
    const float dbias = dvalid ? (branch ? quat_dec_b : lin_dec_b)[dd] : 0.f;

    // ---- register-resident weight fragments: wave wv = gate wv, 32 cols (enc first)
    const i32x4* BpE = (const i32x4*)wfrag + (size_t)(branch * 2) * 131072
                       + ((cg * 4 + wv) * 32) * 64 + lane;
    const i32x4* BpP = BpE + 131072;
    i32x4 bw[32];
#pragma unroll
    for (int kb = 0; kb < 32; ++kb) bw[kb] = BpE[kb * 64];

    float creg[4] = {0.f, 0.f, 0.f, 0.f};
    unsigned int* myslot = bar + (size_t)blk * 16;   // 64 B spacing

    __syncthreads();

    for (int u = 0; u <= NU; ++u) {
        const int is_enc = (u < SS);

        // x loads: read-only, L1-cached, off critical path
        float xv0 = 0.f, xv1 = 0.f, xv2 = 0.f, xv3 = 0.f;
        if (is_enc) {
            const float* xp = x + ((size_t)b * SS + u) * 7 + branch * 3;
            xv0 = xp[0]; xv1 = xp[1]; xv2 = xp[2];
            if (branch) xv3 = xp[3];
        }
        if (u == SS) {      // enc -> pred weight switch (Whh -> Wih)
#pragma unroll
            for (int kb = 0; kb < 32; ++kb) bw[kb] = BpP[kb * 64];
        }

        // ---- group barrier: wave 0 polls the 16 peer flags in parallel (LLC)
        if (u > 0) {
            if (wv == 0) {
                const unsigned int* slot = bar + (size_t)((group << 4) | (lane & 15)) * 16;
                for (;;) {
                    unsigned int v;
                    asm volatile("global_load_dword %0, %1, off sc0 sc1\n\ts_waitcnt vmcnt(0)"
                                 : "=v"(v) : "v"(slot) : "memory");
                    if (__all((int)(v >= (unsigned int)u))) break;
                    __builtin_amdgcn_s_sleep(1);
                }
            }
            __syncthreads();
        }

        // ---- stage A tile (32 rows x 512 h, bf16 fragments) LLC -> LDS, coalesced
        i32x4* lds_cur = lds_a[u & 1];
        {
            const i32x4* gsrc = (const i32x4*)hbuf + (size_t)(u & 1) * 32768
                                + (size_t)branch * 16384 + rg * 2048 + tid;
            i32x4 av[8];
#pragma unroll
            for (int i = 0; i < 8; ++i) av[i] = llc_load_b128(gsrc + i * 256);
            vm_drain();
            __builtin_amdgcn_sched_barrier(0);
#pragma unroll
            for (int i = 0; i < 8; ++i) lds_cur[i * 256 + tid] = av[i];
        }
        __syncthreads();

        if (u == NU) {      // final iteration: only decode h_{NU-1} -> t = NU-2
            if (wv == 3) {
                float s = 0.f;
                if (dvalid) {
                    const unsigned short* hp = (const unsigned short*)lds_cur;
#pragma unroll
                    for (int jj = 0; jj < 64; ++jj) {
                        int j = dseg * 64 + jj;
                        unsigned short hu = hp[(j >> 4) * 512 + ((j >> 3) & 1) * 256 + drow * 8 + (j & 7)];
                        s += __uint_as_float(((unsigned int)hu) << 16) * dwp[j];
                    }
                }
                s += __shfl_xor(s, 8);
                s += __shfl_xor(s, 16);
                s += __shfl_xor(s, 32);
                if (dseg == 0 && dvalid)
                    out[((size_t)(rg * 32 + drow) * NT + (u - 2)) * 7 + branch * 3 + dd] = s + dbias;
            }
            break;
        }

        // ---- GEMM: g[32 x 128] = h[32 x 512] @ W_sliceT; A from LDS (wave-shared),
        //      B from registers (wave wv = gate wv)
        f32x16 acc = {};
        const i32x4* Afrag = lds_cur + lane;
#pragma unroll
        for (int kb = 0; kb < 32; ++kb) {
            i32x4 a0 = Afrag[kb * 64];
            acc = __builtin_amdgcn_mfma_f32_32x32x16_bf16(*(const bf16x8*)&a0, *(const bf16x8*)&bw[kb], acc, 0, 0, 0);
        }
        // C layout (32x32): col = lane&31, row = (reg&3) + 8*(reg>>2) + 4*(lane>>5)
        {
            int col_l = wv * 32 + (lane & 31);
            int rbase = 4 * (lane >> 5);
#pragma unroll
            for (int r = 0; r < 16; ++r) {
                int row_l = rbase + (r & 3) + 8 * (r >> 2);
                g_lds[row_l * 132 + col_l] = acc[r];
            }
        }
        __syncthreads();

        // ---- gates: thread handles row = tid&31, jj = (tid>>5)*4 + p
#pragma unroll
        for (int p = 0; p < 4; ++p) {
            int jj = jbase * 4 + p;
            float gi = g_lds[row * 132 + jj];
            float gf = g_lds[row * 132 + 32 + jj];
            float gc = g_lds[row * 132 + 64 + jj];
            float go = g_lds[row * 132 + 96 + jj];
            if (is_enc) {
                int j4 = jj * 4;
                gi += bEs[jj]      + xv0 * mE[j4]       + xv1 * mE[j4 + 1]       + xv2 * mE[j4 + 2]       + xv3 * mE[j4 + 3];
                gf += bEs[32 + jj] + xv0 * mE[128 + j4] + xv1 * mE[128 + j4 + 1] + xv2 * mE[128 + j4 + 2] + xv3 * mE[128 + j4 + 3];
                gc += bEs[64 + jj] + xv0 * mE[256 + j4] + xv1 * mE[256 + j4 + 1] + xv2 * mE[256 + j4 + 2] + xv3 * mE[256 + j4 + 3];
                go += bEs[96 + jj] + xv0 * mE[384 + j4] + xv1 * mE[384 + j4 + 1] + xv2 * mE[384 + j4 + 2] + xv3 * mE[384 + j4 + 3];
            } else {
                gi += bPs[jj];
                gf += bPs[32 + jj];
                gc += bPs[64 + jj];
                go += bPs[96 + jj];
            }
            float iv = sigm(gi), fv = sigm(gf), gv = tanh_(gc), ov = sigm(go);
            float cn;
            if (is_enc) {
                cn = fv * creg[p] + iv * gv;
                creg[p] = cn;
            } else {
                cn = iv * gv;   // pred steps start from zero state
            }
            h_tile[row * 33 + jj] = ov * tanh_(cn);
        }
        __syncthreads();

        if (wv == 0) {
            // ---- wave 0: pack h_new (bf16, fragment order) -> LLC, then flag
#pragma unroll
            for (int chunk = 0; chunk < 2; ++chunk) {
                int row_l = lane & 31;
                int ch = chunk * 16 + (lane >> 5) * 8;   // h-col base within our 32
                unsigned short us[8];
#pragma unroll
                for (int j = 0; j < 8; ++j) us[j] = f2bf(h_tile[row_l * 33 + ch + j]);
                i32x4 v;
                v.x = us[0] | (us[1] << 16); v.y = us[2] | (us[3] << 16);
                v.z = us[4] | (us[5] << 16); v.w = us[6] | (us[7] << 16);
                int kb = cg * 2 + chunk;
                llc_store_b128((i32x4*)hbuf + (size_t)((u + 1) & 1) * 32768
                               + (size_t)branch * 16384 + rg * 2048 + kb * 64 + lane, v);
            }
            vm_drain();      // h-stores ACKed at LLC before the flag can be written
            if (lane == 0) {
                unsigned int fl = (unsigned int)(u + 1);
                asm volatile("global_store_dword %0, %1, off sc0 sc1" :: "v"(myslot), "v"(fl) : "memory");
            }
        } else if (wv == 3 && u >= 2) {
            // ---- wave 3: decode h_{u-1} (full 512-dot from lds_cur), concurrent with pack
            float s = 0.f;
            if (dvalid) {
                const unsigned short* hp = (const unsigned short*)lds_cur;
#pragma unroll
                for (int jj = 0; jj < 64; ++jj) {
                    int j = dseg * 64 + jj;
                    unsigned short hu = hp[(j >> 4) * 512 + ((j >> 3) & 1) * 256 + drow * 8 + (j & 7)];
                    s += __uint_as_float(((unsigned int)hu) << 16) * dwp[j];
                }
            }
            s += __shfl_xor(s, 8);
            s += __shfl_xor(s, 16);
            s += __shfl_xor(s, 32);
            if (dseg == 0 && dvalid)
                out[((size_t)(rg * 32 + drow) * NT + (u - 2)) * 7 + branch * 3 + dd] = s + dbias;
        }
    }
}

extern "C" void kernel_launch(void* const* d_in, const int* in_sizes, int n_in,
                              void* d_out, int out_size, void* d_ws, size_t ws_size,
                              hipStream_t stream) {
    const float* x          = (const float*)d_in[0];
    const float* lin_enc_w  = (const float*)d_in[1];
    const float* lin_enc_b  = (const float*)d_in[2];
    const float* quat_enc_w = (const float*)d_in[3];
    const float* quat_enc_b = (const float*)d_in[4];
    const float* lin_wih    = (const float*)d_in[5];
    const float* lin_whh    = (const float*)d_in[6];
    const float* lin_bih    = (const float*)d_in[7];
    const float* lin_bhh    = (const float*)d_in[8];
    const float* quat_wih   = (const float*)d_in[9];
    const float* quat_whh   = (const float*)d_in[10];
    const float* quat_bih   = (const float*)d_in[11];
    const float* quat_bhh   = (const float*)d_in[12];
    const float* lin_dec_w  = (const float*)d_in[13];
    const float* lin_dec_b  = (const float*)d_in[14];
    const float* quat_dec_w = (const float*)d_in[15];
    const float* quat_dec_b = (const float*)d_in[16];
    float* out = (float*)d_out;
    char* ws = (char*)d_ws;

    unsigned short* wfrag = (unsigned short*)(ws + 0);
    unsigned short* hbuf  = (unsigned short*)(ws + 8388608ull);
    unsigned int*   bar   = (unsigned int*)(ws + 9437184ull);
    float* M    = (float*)(ws + 10485760ull);
    float* bE   = (float*)(ws + 10551296ull);
    float* bP   = (float*)(ws + 10567680ull);

    k_wfrag<<<2048, 256, 0, stream>>>(lin_whh, lin_wih, quat_whh, quat_wih, wfrag);
    k_mbias<<<16, 256, 0, stream>>>(lin_wih, quat_wih, lin_enc_w, quat_enc_w,
                                    lin_enc_b, quat_enc_b, lin_bih, lin_bhh,
                                    quat_bih, quat_bhh, M, bE, bP);
    k_zero<<<260, 256, 0, stream>>>((i32x4*)(ws + 8388608ull));   // hbuf + bar (flags)

    k_persist<<<256, 256, 0, stream>>>(x, wfrag, M, bE, bP, lin_dec_w, quat_dec_w,
                                       lin_dec_b, quat_dec_b, hbuf, out, bar);
}